// Round 17
// baseline (73.162 us; speedup 1.0000x reference)
//
#include <hip/hip_runtime.h>
#include <hip/hip_bf16.h>

// N=4096, PAIR=2, M=64, D=128, O=128, R=2, MAX_DEG=32
// h = relu(x @ (d*Wsum + W0) + (d*bsum + b0));  out[n] = h0 @ h1^T
//
// Round 16: R15 structure (64.5 KB LDS, 2 barriers/node, upfront x loads,
// DMA-staged W) x 2 nodes per block. After node0's h-barrier the W region
// is dead: issue W(d1) DMA + x(n1) loads there, overlap them with
// GEMM2(n0)+stores, convert, one syncthreads, then node1. Registers are
// free (LDS-bound 2 blocks/CU) so the cross-node xraw costs nothing.

typedef __attribute__((ext_vector_type(8))) short bf16x8;
typedef __attribute__((ext_vector_type(4))) float f32x4;

#define RAW_BARRIER() do {                                   \
    asm volatile("s_waitcnt lgkmcnt(0)" ::: "memory");       \
    __builtin_amdgcn_s_barrier();                            \
    __builtin_amdgcn_sched_barrier(0);                       \
} while (0)

__device__ __forceinline__ unsigned int pkbf(float a, float b) {
    union { __hip_bfloat162 h; unsigned int u; } v;
    v.h = __float22bfloat162_rn(float2{a, b});
    return v.u;
}

__global__ __launch_bounds__(256) void build_weights(
    const float* __restrict__ W_r,  // [2,128,128]
    const float* __restrict__ b_r,  // [2,128]
    const float* __restrict__ W0,   // [128,128]
    const float* __restrict__ b0,   // [128]
    unsigned short* __restrict__ wfrag,  // [32][8*4*64*8]  (32 KB per deg)
    float* __restrict__ call)            // [32*128]
{
    const int t = blockIdx.x * blockDim.x + threadIdx.x;   // 0..65535
    const int d = t >> 11;            // 0..31
    const int r = t & 2047;
    const int k = r >> 4;             // 0..127
    const int o0 = (r & 15) * 8;      // 8-aligned -> ct constant over the 8
    const f32x4* wr0 = (const f32x4*)(W_r + k * 128 + o0);
    const f32x4* wr1 = (const f32x4*)(W_r + 128 * 128 + k * 128 + o0);
    const f32x4* w0p = (const f32x4*)(W0 + k * 128 + o0);
    float w[8];
#pragma unroll
    for (int half = 0; half < 2; ++half) {
        f32x4 a = wr0[half], b = wr1[half], c = w0p[half];
#pragma unroll
        for (int i = 0; i < 4; ++i)
            w[half * 4 + i] = (float)d * (a[i] + b[i]) + c[i];
    }
    const int ct = o0 >> 4;
    const int ks = k >> 5;
    const int lhi = (k >> 3) & 3;
    const int j = k & 7;
    unsigned short* base = wfrag +
        ((((size_t)(d * 8 + ct) * 4 + ks) * 64 + lhi * 16 + (o0 & 15))) * 8 + j;
#pragma unroll
    for (int i = 0; i < 8; ++i) {
        union { float f; unsigned u; } v; v.f = w[i];
        unsigned rr = (v.u + 0x7fffu + ((v.u >> 16) & 1u)) >> 16;
        base[i * 8] = (unsigned short)rr;
    }
    if (t < 32 * 128) {
        int dd = t >> 7, oo = t & 127;
        call[t] = (float)dd * (b_r[oo] + b_r[128 + oo]) + b0[oo];
    }
}

__global__ __launch_bounds__(256) void edge_kernel(
    const float* __restrict__ x,    // [N,2,64,128] f32
    const int* __restrict__ deg,    // [N]
    const unsigned short* __restrict__ wfrag,
    const float* __restrict__ call,
    float* __restrict__ out)        // [N,64,64] f32
{
    // [0,32K): W frags | [32K,64K): h | [64K,+512): bias
    __shared__ char ldsb[66048];

    const int tid = threadIdx.x;
    const int wave = tid >> 6;
    const int lane = tid & 63;
    const int l15 = lane & 15;
    const int lhi = lane >> 4;      // 0..3
    const int rbase = wave * 32;
    const int nb = blockIdx.x * 2;

    const int d0 = deg[nb];
    const int d1 = deg[nb + 1];

    f32x4 xraw[2][4][2];
    bf16x8 afrag[2][4];

    auto stage_w = [&](int d) {
        const char* wsrc = (const char*)(wfrag + (size_t)d * (8 * 4 * 64 * 8));
#pragma unroll
        for (int i = 0; i < 8; ++i) {
            __builtin_amdgcn_global_load_lds(
                (const __attribute__((address_space(1))) unsigned int*)(wsrc + (size_t)i * 4096 + (size_t)tid * 16),
                (__attribute__((address_space(3))) unsigned int*)(ldsb + i * 4096 + wave * 1024),
                16, 0, 0);
        }
        if (tid < 32) {
            __builtin_amdgcn_global_load_lds(
                (const __attribute__((address_space(1))) unsigned int*)(call + d * 128 + tid * 4),
                (__attribute__((address_space(3))) unsigned int*)(ldsb + 65536),
                16, 0, 0);
        }
    };
    auto issue_x = [&](int n) {
        const float* r0p = x + (size_t)n * 16384 + (size_t)(rbase + l15) * 128 + lhi * 8;
#pragma unroll
        for (int ks = 0; ks < 4; ++ks) {
            const f32x4* p0 = (const f32x4*)(r0p + ks * 32);
            const f32x4* p1 = (const f32x4*)(r0p + 2048 + ks * 32);
            xraw[0][ks][0] = p0[0];
            xraw[0][ks][1] = p0[1];
            xraw[1][ks][0] = p1[0];
            xraw[1][ks][1] = p1[1];
        }
    };
    auto convert_x = [&]() {
#pragma unroll
        for (int rt = 0; rt < 2; ++rt)
#pragma unroll
            for (int ks = 0; ks < 4; ++ks) {
                f32x4 a0 = xraw[rt][ks][0];
                f32x4 a1 = xraw[rt][ks][1];
                union { bf16x8 vv; unsigned int uu[4]; } f;
                f.uu[0] = pkbf(a0.x, a0.y);
                f.uu[1] = pkbf(a0.z, a0.w);
                f.uu[2] = pkbf(a1.x, a1.y);
                f.uu[3] = pkbf(a1.z, a1.w);
                afrag[rt][ks] = f.vv;
            }
    };

    // ---- prologue: node 0 ----
    stage_w(d0);
    issue_x(nb);
    convert_x();
    __syncthreads();   // drains staging DMAs; W(d0) + bias visible

    for (int j = 0; j < 2; ++j) {
        // ---- GEMM1 (swapped): D[o][m] = mfma(Wfrag, Xfrag); NO barriers ----
        // h layout: byte = 32768 + ct*4096 + m*32 + slot*16 + (lhi&1)*8,
        //           slot = (lhi>>1) ^ ((m>>2)&1)
#pragma unroll
        for (int ct = 0; ct < 8; ++ct) {
            bf16x8 bfrag[4];
#pragma unroll
            for (int ks = 0; ks < 4; ++ks)
                bfrag[ks] = *(const bf16x8*)(ldsb + ct * 4096 + ks * 1024 + lane * 16);
            f32x4 acc[2] = {{0.f,0.f,0.f,0.f},{0.f,0.f,0.f,0.f}};
#pragma unroll
            for (int ks = 0; ks < 4; ++ks)
#pragma unroll
                for (int rt = 0; rt < 2; ++rt)
                    acc[rt] = __builtin_amdgcn_mfma_f32_16x16x32_bf16(bfrag[ks], afrag[rt][ks], acc[rt], 0, 0, 0);
            const f32x4 cc4 = *(const f32x4*)(ldsb + 65536 + ct * 64 + lhi * 16);
#pragma unroll
            for (int rt = 0; rt < 2; ++rt) {
                const int m = rbase + rt * 16 + l15;
                const int slot = ((lhi >> 1) ^ ((m >> 2) & 1));
                float h0v = fmaxf(acc[rt][0] + cc4.x, 0.f);
                float h1v = fmaxf(acc[rt][1] + cc4.y, 0.f);
                float h2v = fmaxf(acc[rt][2] + cc4.z, 0.f);
                float h3v = fmaxf(acc[rt][3] + cc4.w, 0.f);
                union { unsigned int u[2]; unsigned long long ull; } pk;
                pk.u[0] = pkbf(h0v, h1v);
                pk.u[1] = pkbf(h2v, h3v);
                *(unsigned long long*)(ldsb + 32768 + ct * 4096 + m * 32 + slot * 16 + (lhi & 1) * 8) = pk.ull;
            }
        }
        RAW_BARRIER();   // h visible; all waves past W reads -> W region dead

        // next node's W DMA + x loads fly under GEMM2 (no vmcnt drain here)
        if (j == 0) {
            stage_w(d1);
            issue_x(nb + 1);
        }

        // ---- GEMM2 (swapped): D[q][m] = mfma(h1frag, h0frag) ----
        const int mrow = wave * 16 + l15;     // h0 row (= out row)
        bf16x8 hb[4];
#pragma unroll
        for (int ks = 0; ks < 4; ++ks) {
            const int ct = ks * 2 + (lhi >> 1);
            const int s  = (lhi & 1) ^ ((mrow >> 2) & 1);
            hb[ks] = *(const bf16x8*)(ldsb + 32768 + ct * 4096 + mrow * 32 + s * 16);
        }
        float* outn = out + (size_t)(nb + j) * 4096;
#pragma unroll
        for (int qt = 0; qt < 4; ++qt) {
            const int qrow = 64 + qt * 16 + l15;    // h1 row (= out col base)
            f32x4 acc = {0.f, 0.f, 0.f, 0.f};
#pragma unroll
            for (int ks = 0; ks < 4; ++ks) {
                const int ct = ks * 2 + (lhi >> 1);
                const int s  = (lhi & 1) ^ ((qrow >> 2) & 1);
                bf16x8 ha = *(const bf16x8*)(ldsb + 32768 + ct * 4096 + qrow * 32 + s * 16);
                acc = __builtin_amdgcn_mfma_f32_16x16x32_bf16(ha, hb[ks], acc, 0, 0, 0);
            }
            __builtin_nontemporal_store(acc, (f32x4*)(outn + mrow * 64 + qt * 16 + lhi * 4));
        }

        if (j == 0) {
            convert_x();       // waits x(n1) (drains DMAs too: issued earlier)
            __syncthreads();   // W(d1) + bias visible; h(n0) dead for all waves
        }
    }
}

extern "C" void kernel_launch(void* const* d_in, const int* in_sizes, int n_in,
                              void* d_out, int out_size, void* d_ws, size_t ws_size,
                              hipStream_t stream) {
    const float* x   = (const float*)d_in[0];   // node_features [4096,2,64,128]
    const int*   deg = (const int*)d_in[1];     // [4096]
    const float* W_r = (const float*)d_in[2];   // [2,128,128]
    const float* b_r = (const float*)d_in[3];   // [2,128]
    const float* W0  = (const float*)d_in[4];   // [128,128]
    const float* b0  = (const float*)d_in[5];   // [128]
    float* out = (float*)d_out;                 // [4096,64,64]

    unsigned short* wfrag = (unsigned short*)d_ws;                    // 1 MB
    float* call = (float*)((unsigned short*)d_ws + 32 * 8 * 4 * 64 * 8); // +16 KB

    build_weights<<<256, 256, 0, stream>>>(W_r, b_r, W0, b0, wfrag, call);
    edge_kernel<<<2048, 256, 0, stream>>>(x, deg, wfrag, call, out);
}

// Round 18
// 69.389 us; speedup vs baseline: 1.0544x; 1.0544x over previous
//
#include <hip/hip_runtime.h>
#include <hip/hip_bf16.h>

// N=4096, PAIR=2, M=64, D=128, O=128, R=2, MAX_DEG=32
// h = relu(x @ (d*Wsum + W0) + (d*bsum + b0));  out[n] = h0 @ h1^T
//
// Round 17: R15 structure (2 barriers, DMA-staged W, upfront x loads,
// 64.5 KB LDS, 2 blocks/CU) at 512 threads/block: 8 waves x 16 rows each
// -> 4 waves/SIMD (was 2). Per-wave serial work halves; scheduler gets 2x
// wave candidates to hide HBM latency. Work split:
//   GEMM1: wave w owns h rows w*16..w*16+15 (all 8 ct), 32 MFMAs.
//   GEMM2: wave w owns out m-tile (w>>1), q-tiles {2*(w&1), 2*(w&1)+1}.

typedef __attribute__((ext_vector_type(8))) short bf16x8;
typedef __attribute__((ext_vector_type(4))) float f32x4;

#define RAW_BARRIER() do {                                   \
    asm volatile("s_waitcnt lgkmcnt(0)" ::: "memory");       \
    __builtin_amdgcn_s_barrier();                            \
    __builtin_amdgcn_sched_barrier(0);                       \
} while (0)

__device__ __forceinline__ unsigned int pkbf(float a, float b) {
    union { __hip_bfloat162 h; unsigned int u; } v;
    v.h = __float22bfloat162_rn(float2{a, b});
    return v.u;
}

__global__ __launch_bounds__(256) void build_weights(
    const float* __restrict__ W_r,  // [2,128,128]
    const float* __restrict__ b_r,  // [2,128]
    const float* __restrict__ W0,   // [128,128]
    const float* __restrict__ b0,   // [128]
    unsigned short* __restrict__ wfrag,  // [32][8*4*64*8]  (32 KB per deg)
    float* __restrict__ call)            // [32*128]
{
    const int t = blockIdx.x * blockDim.x + threadIdx.x;   // 0..65535
    const int d = t >> 11;            // 0..31
    const int r = t & 2047;
    const int k = r >> 4;             // 0..127
    const int o0 = (r & 15) * 8;      // 8-aligned -> ct constant over the 8
    const f32x4* wr0 = (const f32x4*)(W_r + k * 128 + o0);
    const f32x4* wr1 = (const f32x4*)(W_r + 128 * 128 + k * 128 + o0);
    const f32x4* w0p = (const f32x4*)(W0 + k * 128 + o0);
    float w[8];
#pragma unroll
    for (int half = 0; half < 2; ++half) {
        f32x4 a = wr0[half], b = wr1[half], c = w0p[half];
#pragma unroll
        for (int i = 0; i < 4; ++i)
            w[half * 4 + i] = (float)d * (a[i] + b[i]) + c[i];
    }
    const int ct = o0 >> 4;
    const int ks = k >> 5;
    const int lhi = (k >> 3) & 3;
    const int j = k & 7;
    unsigned short* base = wfrag +
        ((((size_t)(d * 8 + ct) * 4 + ks) * 64 + lhi * 16 + (o0 & 15))) * 8 + j;
#pragma unroll
    for (int i = 0; i < 8; ++i) {
        union { float f; unsigned u; } v; v.f = w[i];
        unsigned rr = (v.u + 0x7fffu + ((v.u >> 16) & 1u)) >> 16;
        base[i * 8] = (unsigned short)rr;
    }
    if (t < 32 * 128) {
        int dd = t >> 7, oo = t & 127;
        call[t] = (float)dd * (b_r[oo] + b_r[128 + oo]) + b0[oo];
    }
}

__global__ __launch_bounds__(512) void edge_kernel(
    const float* __restrict__ x,    // [N,2,64,128] f32
    const int* __restrict__ deg,    // [N]
    const unsigned short* __restrict__ wfrag,
    const float* __restrict__ call,
    float* __restrict__ out)        // [N,64,64] f32
{
    // [0,32K): W frags | [32K,64K): h | [64K,+512): bias
    __shared__ char ldsb[66048];

    const int n = blockIdx.x;
    const int tid = threadIdx.x;
    const int wave = tid >> 6;      // 0..7
    const int lane = tid & 63;
    const int l15 = lane & 15;
    const int lhi = lane >> 4;      // 0..3
    const int d = deg[n];

    const float* xn = x + (size_t)n * (2 * 64 * 128);
    const char* wsrc = (const char*)(wfrag + (size_t)d * (8 * 4 * 64 * 8));

    // ---- W staging: global -> LDS direct (identity copy of 32 KB) ----
    // 512 threads x 16 B x 4 instrs; dest = i*8192 + wave*1024 + lane*16
#pragma unroll
    for (int i = 0; i < 4; ++i) {
        __builtin_amdgcn_global_load_lds(
            (const __attribute__((address_space(1))) unsigned int*)(wsrc + (size_t)i * 8192 + (size_t)tid * 16),
            (__attribute__((address_space(3))) unsigned int*)(ldsb + i * 8192 + wave * 1024),
            16, 0, 0);
    }
    // ---- bias staging: 512 B ----
    if (tid < 32) {
        __builtin_amdgcn_global_load_lds(
            (const __attribute__((address_space(1))) unsigned int*)(call + d * 128 + tid * 4),
            (__attribute__((address_space(3))) unsigned int*)(ldsb + 65536),
            16, 0, 0);
    }

    // ---- x: wave owns rows wave*16..+15; all 8 loads upfront, convert ----
    const float* r0p = xn + (size_t)(wave * 16 + l15) * 128 + lhi * 8;
    f32x4 xraw[4][2];
#pragma unroll
    for (int ks = 0; ks < 4; ++ks) {
        const f32x4* p0 = (const f32x4*)(r0p + ks * 32);
        xraw[ks][0] = p0[0];
        xraw[ks][1] = p0[1];
    }
    bf16x8 afrag[4];
#pragma unroll
    for (int ks = 0; ks < 4; ++ks) {
        f32x4 a0 = xraw[ks][0];
        f32x4 a1 = xraw[ks][1];
        union { bf16x8 vv; unsigned int uu[4]; } f;
        f.uu[0] = pkbf(a0.x, a0.y);
        f.uu[1] = pkbf(a0.z, a0.w);
        f.uu[2] = pkbf(a1.x, a1.y);
        f.uu[3] = pkbf(a1.z, a1.w);
        afrag[ks] = f.vv;
    }

    __syncthreads();   // drains staging DMAs; W + bias visible  [barrier 1/2]

    // ---- GEMM1 (swapped): D[o][m] = mfma(Wfrag, Xfrag); NO barriers ----
    // h layout: byte = 32768 + ct*4096 + m*32 + slot*16 + (lhi&1)*8,
    //           slot = (lhi>>1) ^ ((m>>2)&1)
#pragma unroll
    for (int ct = 0; ct < 8; ++ct) {
        bf16x8 bfrag[4];
#pragma unroll
        for (int ks = 0; ks < 4; ++ks)
            bfrag[ks] = *(const bf16x8*)(ldsb + ct * 4096 + ks * 1024 + lane * 16);
        f32x4 acc = {0.f, 0.f, 0.f, 0.f};
#pragma unroll
        for (int ks = 0; ks < 4; ++ks)
            acc = __builtin_amdgcn_mfma_f32_16x16x32_bf16(bfrag[ks], afrag[ks], acc, 0, 0, 0);
        const f32x4 cc4 = *(const f32x4*)(ldsb + 65536 + ct * 64 + lhi * 16);
        const int m = wave * 16 + l15;
        const int slot = ((lhi >> 1) ^ ((m >> 2) & 1));
        float h0v = fmaxf(acc[0] + cc4.x, 0.f);
        float h1v = fmaxf(acc[1] + cc4.y, 0.f);
        float h2v = fmaxf(acc[2] + cc4.z, 0.f);
        float h3v = fmaxf(acc[3] + cc4.w, 0.f);
        union { unsigned int u[2]; unsigned long long ull; } pk;
        pk.u[0] = pkbf(h0v, h1v);
        pk.u[1] = pkbf(h2v, h3v);
        *(unsigned long long*)(ldsb + 32768 + ct * 4096 + m * 32 + slot * 16 + (lhi & 1) * 8) = pk.ull;
    }
    RAW_BARRIER();   // h fully visible  [barrier 2/2]

    // ---- GEMM2 (swapped): D[q][m] = mfma(h1frag, h0frag) ----
    // wave w: m-tile (w>>1), q-tiles {2*(w&1), 2*(w&1)+1}
    const int mrow = (wave >> 1) * 16 + l15;    // h0 row (= out row)
    bf16x8 hb[4];
#pragma unroll
    for (int ks = 0; ks < 4; ++ks) {
        const int ct = ks * 2 + (lhi >> 1);
        const int s  = (lhi & 1) ^ ((mrow >> 2) & 1);
        hb[ks] = *(const bf16x8*)(ldsb + 32768 + ct * 4096 + mrow * 32 + s * 16);
    }
    float* outn = out + (size_t)n * 4096;
#pragma unroll
    for (int q = 0; q < 2; ++q) {
        const int qt = (wave & 1) * 2 + q;
        const int qrow = 64 + qt * 16 + l15;    // h1 row (= out col base)
        f32x4 acc = {0.f, 0.f, 0.f, 0.f};
#pragma unroll
        for (int ks = 0; ks < 4; ++ks) {
            const int ct = ks * 2 + (lhi >> 1);
            const int s  = (lhi & 1) ^ ((qrow >> 2) & 1);
            bf16x8 ha = *(const bf16x8*)(ldsb + 32768 + ct * 4096 + qrow * 32 + s * 16);
            acc = __builtin_amdgcn_mfma_f32_16x16x32_bf16(ha, hb[ks], acc, 0, 0, 0);
        }
        __builtin_nontemporal_store(acc, (f32x4*)(outn + mrow * 64 + qt * 16 + lhi * 4));
    }
}

extern "C" void kernel_launch(void* const* d_in, const int* in_sizes, int n_in,
                              void* d_out, int out_size, void* d_ws, size_t ws_size,
                              hipStream_t stream) {
    const float* x   = (const float*)d_in[0];   // node_features [4096,2,64,128]
    const int*   deg = (const int*)d_in[1];     // [4096]
    const float* W_r = (const float*)d_in[2];   // [2,128,128]
    const float* b_r = (const float*)d_in[3];   // [2,128]
    const float* W0  = (const float*)d_in[4];   // [128,128]
    const float* b0  = (const float*)d_in[5];   // [128]
    float* out = (float*)d_out;                 // [4096,64,64]

    unsigned short* wfrag = (unsigned short*)d_ws;                    // 1 MB
    float* call = (float*)((unsigned short*)d_ws + 32 * 8 * 4 * 64 * 8); // +16 KB

    build_weights<<<256, 256, 0, stream>>>(W_r, b_r, W0, b0, wfrag, call);
    edge_kernel<<<4096, 512, 0, stream>>>(x, deg, wfrag, call, out);
}